// Round 11
// baseline (284.524 us; speedup 1.0000x reference)
//
#include <hip/hip_runtime.h>

// QuantizedLinear on MI355X — round 11: r10 + 2-phase interleave + setprio.
//   out = (x @ H) @ dequant(W)^T + bias
// Both GEMMs single-term bf16 (validated r8-r10): GEMM1 xh·Hh, GEMM2 xrh·Wb,
// Wb = bf16((nibble-8)*scale).
// r10 frame (proven): 256x256 tile, BK=32, 8 waves (2Mx4N), 4-slot LDS ring
// (128 KiB), counted vmcnt(4) (never 0 in main loop), 64 B-row XOR swizzle
// both-sides (0 conflicts), XCD swizzle.
// NEW (r10 PMC: MFMA pipe 53% + LDS pipe ~52% busy but serialized — all 8
// waves burst reads together then all MFMA together): split each K-tile into
// 2 phases {ds_read subtile; stage pair; barrier; setprio(1); 16 MFMA;
// setprio(0); barrier} so one wave's reads overlap another's MFMA (m196/m201
// pattern), with vmcnt(4) once per tile at P1's end. sched_barrier(0) pins
// phase boundaries only; compiler keeps fine-grained lgkmcnt within phases.
// Requires 128 MiB d_ws (192 proven).

#define N_TOK 4096
#define K_DIM 4096
#define M_DIM 4096
#define NT    128          // K tiles (4096/32)

typedef __attribute__((ext_vector_type(8))) short s8v;       // 8 bf16 (4 VGPR)
typedef __attribute__((ext_vector_type(4))) float f32x4;
typedef __attribute__((ext_vector_type(4))) unsigned short u16x4;
typedef __attribute__((ext_vector_type(8))) unsigned short u16x8;

#define AS1(p) ((const __attribute__((address_space(1))) void*)(p))
#define AS3(p) ((__attribute__((address_space(3))) void*)(p))

__device__ __forceinline__ unsigned short bf16_rne(float f) {
    unsigned int u = __float_as_uint(f);
    unsigned int r = (u + 0x7FFFu + ((u >> 16) & 1u)) >> 16;
    return (unsigned short)r;
}

// ---------- prep: cast fp32 -> bf16 (RNE), x8 vectorized ----------
__global__ __launch_bounds__(256) void prep_cast(const float* __restrict__ in,
                                                 unsigned short* __restrict__ ph) {
    size_t i = ((size_t)blockIdx.x * 256 + threadIdx.x) * 8;
    float4 v0 = *reinterpret_cast<const float4*>(&in[i]);
    float4 v1 = *reinterpret_cast<const float4*>(&in[i + 4]);
    u16x8 h;
    h[0] = bf16_rne(v0.x); h[1] = bf16_rne(v0.y);
    h[2] = bf16_rne(v0.z); h[3] = bf16_rne(v0.w);
    h[4] = bf16_rne(v1.x); h[5] = bf16_rne(v1.y);
    h[6] = bf16_rne(v1.z); h[7] = bf16_rne(v1.w);
    *reinterpret_cast<u16x8*>(&ph[i]) = h;
}

// ---------- prep: transpose H -> Th (bf16) stored [n][k] ----------
__global__ __launch_bounds__(256) void prep_hT(const float* __restrict__ H,
                                               unsigned short* __restrict__ Th) {
    __shared__ float tile[64][65];
    const int t = threadIdx.x;
    const int tx = t & 15, ty = t >> 4;
    const int c0 = blockIdx.x * 64, r0 = blockIdx.y * 64;
    #pragma unroll
    for (int rr = 0; rr < 4; ++rr) {
        int r = ty + rr * 16;
        float4 v = *reinterpret_cast<const float4*>(&H[(size_t)(r0 + r) * K_DIM + c0 + tx * 4]);
        tile[r][tx * 4 + 0] = v.x;
        tile[r][tx * 4 + 1] = v.y;
        tile[r][tx * 4 + 2] = v.z;
        tile[r][tx * 4 + 3] = v.w;
    }
    __syncthreads();
    #pragma unroll
    for (int rr = 0; rr < 4; ++rr) {
        int c = ty + rr * 16;
        u16x4 h;
        #pragma unroll
        for (int e = 0; e < 4; ++e) h[e] = bf16_rne(tile[tx * 4 + e][c]);
        size_t o = (size_t)(c0 + c) * K_DIM + r0 + tx * 4;
        *reinterpret_cast<u16x4*>(&Th[o]) = h;
    }
}

// ---------- prep: dequant int4 -> bf16 (nibble-8)*scale ----------
__global__ __launch_bounds__(256) void prep_w(const int* __restrict__ wd,
                                              const float* __restrict__ ws,
                                              unsigned short* __restrict__ Wb) {
    const int o = blockIdx.x, t = threadIdx.x;
    const int4* p = reinterpret_cast<const int4*>(&wd[(size_t)o * (K_DIM / 2) + t * 8]);
    int4 w0 = p[0], w1 = p[1];
    const float s = ws[o * 32 + (t >> 3)];   // k0 = t*16, group = t*16/128
    int wv[8] = {w0.x, w0.y, w0.z, w0.w, w1.x, w1.y, w1.z, w1.w};
    u16x8 h0, h1;
    #pragma unroll
    for (int m = 0; m < 8; ++m) {
        unsigned short lo = bf16_rne((float)((wv[m] & 0xF) - 8) * s);
        unsigned short hi = bf16_rne((float)(((wv[m] >> 4) & 0xF) - 8) * s);
        if (m < 4) { h0[2 * m] = lo; h0[2 * m + 1] = hi; }
        else       { h1[2 * (m - 4)] = lo; h1[2 * (m - 4) + 1] = hi; }
    }
    size_t oo = (size_t)o * K_DIM + t * 16;
    *reinterpret_cast<u16x8*>(&Wb[oo]) = h0;
    *reinterpret_cast<u16x8*>(&Wb[oo + 8]) = h1;
}

// ---------- 256x256 GEMM, BK=32, counted-vmcnt ring + 2-phase interleave ----------
// A [m][k] bf16, B [n][k] bf16. 8 waves 2x4; wave owns 128x64 (8x4 frags).
// MODE 0: C -> bf16 (Cb).  MODE 1: C -> f32 + bias (Cf).
template <int MODE>
__global__ __launch_bounds__(512) void gemm_cv(const unsigned short* __restrict__ A,
                                               const unsigned short* __restrict__ B,
                                               const float* __restrict__ bias,
                                               unsigned short* __restrict__ Cb,
                                               float* __restrict__ Cf) {
    extern __shared__ unsigned short sm[];   // 4 slots x (A 8192 | B 8192) ushorts
    const int t = threadIdx.x;
    const int lane = t & 63;
    const int wid = __builtin_amdgcn_readfirstlane(t >> 6);
    const int wr = wid >> 2, wc = wid & 3;   // 2 x 4 wave grid

    // XCD-aware bijective swizzle: 256 blocks, 8 XCDs, 256%8==0
    const int fid = blockIdx.x;
    const int sw = (fid & 7) * 32 + (fid >> 3);
    const int bm = (sw >> 4) * 256;
    const int bn = (sw & 15) * 256;

    // staging: per matrix tile 1024 chunks (256 rows x 4 chunks of 16B),
    // 2 chunks/thread. LDS dest linear; SOURCE pre-swizzled:
    // logical chunk = physical ^ ((row>>1)&3)  (r4/r6/r10 proven-zero layout).
    size_t ga[2], gb[2];
    int lb[2];
    #pragma unroll
    for (int j = 0; j < 2; ++j) {
        int ch = wid * 128 + j * 64 + lane;
        int row = ch >> 2, qp = ch & 3;
        int qs = qp ^ ((row >> 1) & 3);
        ga[j] = (size_t)(bm + row) * K_DIM + qs * 8;
        gb[j] = (size_t)(bn + row) * K_DIM + qs * 8;
        lb[j] = (wid * 128 + j * 64) * 8;    // wave-uniform, HW adds lane*16B
    }

    // fragment reads: row r, chunk lk -> physical lk ^ ((r>>1)&3)
    const int lr = lane & 15, lk = lane >> 4;
    int aoff[8], boff[4], colj[4];
    #pragma unroll
    for (int i = 0; i < 8; ++i) {
        int ra = wr * 128 + i * 16 + lr;
        aoff[i] = ra * 32 + (lk ^ ((ra >> 1) & 3)) * 8;
    }
    #pragma unroll
    for (int j = 0; j < 4; ++j) {
        int rb = wc * 64 + j * 16 + lr;
        boff[j] = rb * 32 + (lk ^ ((rb >> 1) & 3)) * 8;
        colj[j] = bn + wc * 64 + j * 16 + lr;
    }

    f32x4 acc[8][4];
    #pragma unroll
    for (int i = 0; i < 8; ++i)
        #pragma unroll
        for (int j = 0; j < 4; ++j) acc[i][j] = {0.f, 0.f, 0.f, 0.f};

#define LD8(p) (*reinterpret_cast<const s8v*>(p))

#define STAGE_AB(tt)                                                                                   \
    {                                                                                                  \
        const int _sl = ((tt) & 3) * 16384;                                                            \
        _Pragma("unroll")                                                                              \
        for (int j = 0; j < 2; ++j) {                                                                  \
            __builtin_amdgcn_global_load_lds(AS1(A + ga[j] + (tt) * 32), AS3(&sm[_sl + lb[j]]), 16, 0, 0); \
            __builtin_amdgcn_global_load_lds(AS1(B + gb[j] + (tt) * 32), AS3(&sm[_sl + 8192 + lb[j]]), 16, 0, 0); \
        }                                                                                              \
    }

#define STAGE_A(tt)                                                                                    \
    {                                                                                                  \
        const int _sl = ((tt) & 3) * 16384;                                                            \
        _Pragma("unroll")                                                                              \
        for (int j = 0; j < 2; ++j)                                                                    \
            __builtin_amdgcn_global_load_lds(AS1(A + ga[j] + (tt) * 32), AS3(&sm[_sl + lb[j]]), 16, 0, 0); \
    }

#define STAGE_B(tt)                                                                                    \
    {                                                                                                  \
        const int _sl = ((tt) & 3) * 16384;                                                            \
        _Pragma("unroll")                                                                              \
        for (int j = 0; j < 2; ++j)                                                                    \
            __builtin_amdgcn_global_load_lds(AS1(B + gb[j] + (tt) * 32), AS3(&sm[_sl + 8192 + lb[j]]), 16, 0, 0); \
    }

#define COMPUTE(tt)                                                                                    \
    {                                                                                                  \
        const unsigned short* _pa = &sm[((tt) & 3) * 16384];                                           \
        const unsigned short* _pb = _pa + 8192;                                                        \
        s8v av[8], bv[4];                                                                              \
        _Pragma("unroll")                                                                              \
        for (int i = 0; i < 8; ++i) av[i] = LD8(&_pa[aoff[i]]);                                        \
        _Pragma("unroll")                                                                              \
        for (int j = 0; j < 4; ++j) bv[j] = LD8(&_pb[boff[j]]);                                        \
        _Pragma("unroll")                                                                              \
        for (int i = 0; i < 8; ++i)                                                                    \
            _Pragma("unroll")                                                                          \
            for (int j = 0; j < 4; ++j)                                                                \
                acc[i][j] = __builtin_amdgcn_mfma_f32_16x16x32_bf16(av[i], bv[j], acc[i][j], 0, 0, 0); \
    }

#define SYNCN(N)                                                                                       \
    asm volatile("s_waitcnt vmcnt(" #N ")" ::: "memory");                                              \
    __builtin_amdgcn_s_barrier();                                                                      \
    __builtin_amdgcn_sched_barrier(0);

#define PHASE_BAR()                                                                                    \
    __builtin_amdgcn_s_barrier();                                                                      \
    __builtin_amdgcn_sched_barrier(0);

    // prologue: stage tiles 0,1; retire tile 0 (vmcnt(4) leaves tile 1 in flight)
    STAGE_AB(0);
    STAGE_AB(1);
    SYNCN(4);
    // steady state, 2 phases/tile:
    //   P0: read bv + av[0..3]; issue A-stage(t+2); bar; prio1; 16 MFMA; prio0; bar
    //   P1: read av[4..7];      issue B-stage(t+2); bar; prio1; 16 MFMA; prio0;
    //       vmcnt(4) (retire t+1's 4 loads; t+2's 4 stay in flight); bar
    for (int t = 0; t + 2 < NT; ++t) {
        const unsigned short* pa = &sm[(t & 3) * 16384];
        const unsigned short* pb = pa + 8192;
        s8v bv[4], a0[4], a1[4];
        #pragma unroll
        for (int j = 0; j < 4; ++j) bv[j] = LD8(&pb[boff[j]]);
        #pragma unroll
        for (int i = 0; i < 4; ++i) a0[i] = LD8(&pa[aoff[i]]);
        STAGE_A(t + 2);
        PHASE_BAR();
        __builtin_amdgcn_s_setprio(1);
        #pragma unroll
        for (int i = 0; i < 4; ++i)
            #pragma unroll
            for (int j = 0; j < 4; ++j)
                acc[i][j] = __builtin_amdgcn_mfma_f32_16x16x32_bf16(a0[i], bv[j], acc[i][j], 0, 0, 0);
        __builtin_amdgcn_s_setprio(0);
        PHASE_BAR();
        #pragma unroll
        for (int i = 0; i < 4; ++i) a1[i] = LD8(&pa[aoff[4 + i]]);
        STAGE_B(t + 2);
        PHASE_BAR();
        __builtin_amdgcn_s_setprio(1);
        #pragma unroll
        for (int i = 0; i < 4; ++i)
            #pragma unroll
            for (int j = 0; j < 4; ++j)
                acc[4 + i][j] = __builtin_amdgcn_mfma_f32_16x16x32_bf16(a1[i], bv[j], acc[4 + i][j], 0, 0, 0);
        __builtin_amdgcn_s_setprio(0);
        SYNCN(4);
    }
    // tail (no further staging)
    COMPUTE(NT - 2);
    SYNCN(0);          // retire tile NT-1 (last 4 loads)
    COMPUTE(NT - 1);
#undef STAGE_AB
#undef STAGE_A
#undef STAGE_B
#undef COMPUTE
#undef SYNCN
#undef PHASE_BAR
#undef LD8

    // epilogue — C/D frag layout: col = lane&15, row = (lane>>4)*4 + reg  [m89]
    if (MODE == 0) {
        #pragma unroll
        for (int i = 0; i < 8; ++i)
            #pragma unroll
            for (int j = 0; j < 4; ++j)
                #pragma unroll
                for (int r = 0; r < 4; ++r) {
                    int row = bm + wr * 128 + i * 16 + lk * 4 + r;
                    Cb[(size_t)row * K_DIM + colj[j]] = bf16_rne(acc[i][j][r]);
                }
    } else {
        float bj[4];
        #pragma unroll
        for (int j = 0; j < 4; ++j) bj[j] = bias[colj[j]];
        #pragma unroll
        for (int i = 0; i < 8; ++i)
            #pragma unroll
            for (int j = 0; j < 4; ++j)
                #pragma unroll
                for (int r = 0; r < 4; ++r) {
                    int row = bm + wr * 128 + i * 16 + lk * 4 + r;
                    Cf[(size_t)row * M_DIM + colj[j]] = acc[i][j][r] + bj[j];
                }
    }
}

extern "C" void kernel_launch(void* const* d_in, const int* in_sizes, int n_in,
                              void* d_out, int out_size, void* d_ws, size_t ws_size,
                              hipStream_t stream) {
    const float* x      = (const float*)d_in[0];
    const float* had    = (const float*)d_in[1];
    const float* wscale = (const float*)d_in[2];
    const float* bias   = (const float*)d_in[3];
    const int*   wdata  = (const int*)d_in[4];
    float* out = (float*)d_out;

    const size_t SEG = (size_t)N_TOK * K_DIM * 2;   // 32 MiB
    char* w = (char*)d_ws;
    unsigned short* xh  = (unsigned short*)(w);            // [0,32Mi)
    unsigned short* Hh  = (unsigned short*)(w + SEG);      // [32,64Mi)
    unsigned short* xrh = (unsigned short*)(w + 2 * SEG);  // [64,96Mi)
    unsigned short* Wb  = (unsigned short*)(w + 3 * SEG);  // [96,128Mi)

    // allow 128 KiB dynamic LDS (host-side idempotent config; guarded so the
    // graph-captured replay path never re-executes it — proven r10)
    static bool attr_done = false;
    if (!attr_done) {
        hipFuncSetAttribute((const void*)gemm_cv<0>,
                            hipFuncAttributeMaxDynamicSharedMemorySize, 131072);
        hipFuncSetAttribute((const void*)gemm_cv<1>,
                            hipFuncAttributeMaxDynamicSharedMemorySize, 131072);
        attr_done = true;
    }

    prep_cast<<<(N_TOK * K_DIM) / (256 * 8), 256, 0, stream>>>(x, xh);
    prep_hT<<<dim3(64, 64), 256, 0, stream>>>(had, Hh);
    prep_w<<<M_DIM, 256, 0, stream>>>(wdata, wscale, Wb);
    gemm_cv<0><<<256, 512, 131072, stream>>>(xh, Hh, nullptr, xrh, nullptr);
    gemm_cv<1><<<256, 512, 131072, stream>>>(xrh, Wb, bias, nullptr, out);
}

// Round 12
// 281.190 us; speedup vs baseline: 1.0119x; 1.0119x over previous
//
#include <hip/hip_runtime.h>

// QuantizedLinear on MI355X — round 12: r10 frame + 3-deep prefetch ring.
//   out = (x @ H) @ dequant(W)^T + bias
// Both GEMMs single-term bf16 (validated r8-r10): GEMM1 xh·Hh, GEMM2 xrh·Wb,
// Wb = bf16((nibble-8)*scale).
// r10 PMC re-analysis: tile time 2212 cyc ≈ 32 KiB staged / 14.5 B/cyc/CU —
// the loop is paced by staging DELIVERY, which scales with in-flight load
// depth (r8 2-blk/CU: 20.6 B/cyc; HK 256²: ~24). r11's compute-side phasing
// was null because it never touched this. Fix: use the ring's idle 4th slot —
// stage THREE tiles ahead: {STAGE(t+3); COMPUTE(t); vmcnt(8)+barrier}.
// Per-wave in-flight 4-8 -> 8-12 loads (~80 KiB/CU). Invariants: iter issues
// 4, retires oldest 4 (t+1's), leaves 8 (t+2,t+3) in flight — never below 8
// in steady state (T4). WAR: slot(t+3)=(t-1)&3 last read in iter t-1,
// separated by that iter's barrier. Tail drains 8->4->0.
// 256x256 tile, BK=32, 8 waves (2Mx4N), 128 KiB LDS ring, 64 B-row XOR
// swizzle both-sides (0 conflicts), XCD swizzle. No phase barriers/setprio
// (r11: negative). Requires 128 MiB d_ws (192 proven).

#define N_TOK 4096
#define K_DIM 4096
#define M_DIM 4096
#define NT    128          // K tiles (4096/32)

typedef __attribute__((ext_vector_type(8))) short s8v;       // 8 bf16 (4 VGPR)
typedef __attribute__((ext_vector_type(4))) float f32x4;
typedef __attribute__((ext_vector_type(4))) unsigned short u16x4;
typedef __attribute__((ext_vector_type(8))) unsigned short u16x8;

#define AS1(p) ((const __attribute__((address_space(1))) void*)(p))
#define AS3(p) ((__attribute__((address_space(3))) void*)(p))

__device__ __forceinline__ unsigned short bf16_rne(float f) {
    unsigned int u = __float_as_uint(f);
    unsigned int r = (u + 0x7FFFu + ((u >> 16) & 1u)) >> 16;
    return (unsigned short)r;
}

// ---------- prep: cast fp32 -> bf16 (RNE), x8 vectorized ----------
__global__ __launch_bounds__(256) void prep_cast(const float* __restrict__ in,
                                                 unsigned short* __restrict__ ph) {
    size_t i = ((size_t)blockIdx.x * 256 + threadIdx.x) * 8;
    float4 v0 = *reinterpret_cast<const float4*>(&in[i]);
    float4 v1 = *reinterpret_cast<const float4*>(&in[i + 4]);
    u16x8 h;
    h[0] = bf16_rne(v0.x); h[1] = bf16_rne(v0.y);
    h[2] = bf16_rne(v0.z); h[3] = bf16_rne(v0.w);
    h[4] = bf16_rne(v1.x); h[5] = bf16_rne(v1.y);
    h[6] = bf16_rne(v1.z); h[7] = bf16_rne(v1.w);
    *reinterpret_cast<u16x8*>(&ph[i]) = h;
}

// ---------- prep: transpose H -> Th (bf16) stored [n][k] ----------
__global__ __launch_bounds__(256) void prep_hT(const float* __restrict__ H,
                                               unsigned short* __restrict__ Th) {
    __shared__ float tile[64][65];
    const int t = threadIdx.x;
    const int tx = t & 15, ty = t >> 4;
    const int c0 = blockIdx.x * 64, r0 = blockIdx.y * 64;
    #pragma unroll
    for (int rr = 0; rr < 4; ++rr) {
        int r = ty + rr * 16;
        float4 v = *reinterpret_cast<const float4*>(&H[(size_t)(r0 + r) * K_DIM + c0 + tx * 4]);
        tile[r][tx * 4 + 0] = v.x;
        tile[r][tx * 4 + 1] = v.y;
        tile[r][tx * 4 + 2] = v.z;
        tile[r][tx * 4 + 3] = v.w;
    }
    __syncthreads();
    #pragma unroll
    for (int rr = 0; rr < 4; ++rr) {
        int c = ty + rr * 16;
        u16x4 h;
        #pragma unroll
        for (int e = 0; e < 4; ++e) h[e] = bf16_rne(tile[tx * 4 + e][c]);
        size_t o = (size_t)(c0 + c) * K_DIM + r0 + tx * 4;
        *reinterpret_cast<u16x4*>(&Th[o]) = h;
    }
}

// ---------- prep: dequant int4 -> bf16 (nibble-8)*scale ----------
__global__ __launch_bounds__(256) void prep_w(const int* __restrict__ wd,
                                              const float* __restrict__ ws,
                                              unsigned short* __restrict__ Wb) {
    const int o = blockIdx.x, t = threadIdx.x;
    const int4* p = reinterpret_cast<const int4*>(&wd[(size_t)o * (K_DIM / 2) + t * 8]);
    int4 w0 = p[0], w1 = p[1];
    const float s = ws[o * 32 + (t >> 3)];   // k0 = t*16, group = t*16/128
    int wv[8] = {w0.x, w0.y, w0.z, w0.w, w1.x, w1.y, w1.z, w1.w};
    u16x8 h0, h1;
    #pragma unroll
    for (int m = 0; m < 8; ++m) {
        unsigned short lo = bf16_rne((float)((wv[m] & 0xF) - 8) * s);
        unsigned short hi = bf16_rne((float)(((wv[m] >> 4) & 0xF) - 8) * s);
        if (m < 4) { h0[2 * m] = lo; h0[2 * m + 1] = hi; }
        else       { h1[2 * (m - 4)] = lo; h1[2 * (m - 4) + 1] = hi; }
    }
    size_t oo = (size_t)o * K_DIM + t * 16;
    *reinterpret_cast<u16x8*>(&Wb[oo]) = h0;
    *reinterpret_cast<u16x8*>(&Wb[oo + 8]) = h1;
}

// ---------- 256x256 GEMM, BK=32, counted-vmcnt 4-slot ring, depth-3 ----------
// A [m][k] bf16, B [n][k] bf16. 8 waves 2x4; wave owns 128x64 (8x4 frags).
// MODE 0: C -> bf16 (Cb).  MODE 1: C -> f32 + bias (Cf).
template <int MODE>
__global__ __launch_bounds__(512) void gemm_cv(const unsigned short* __restrict__ A,
                                               const unsigned short* __restrict__ B,
                                               const float* __restrict__ bias,
                                               unsigned short* __restrict__ Cb,
                                               float* __restrict__ Cf) {
    extern __shared__ unsigned short sm[];   // 4 slots x (A 8192 | B 8192) ushorts
    const int t = threadIdx.x;
    const int lane = t & 63;
    const int wid = __builtin_amdgcn_readfirstlane(t >> 6);
    const int wr = wid >> 2, wc = wid & 3;   // 2 x 4 wave grid

    // XCD-aware bijective swizzle: 256 blocks, 8 XCDs, 256%8==0
    const int fid = blockIdx.x;
    const int sw = (fid & 7) * 32 + (fid >> 3);
    const int bm = (sw >> 4) * 256;
    const int bn = (sw & 15) * 256;

    // staging: per matrix tile 1024 chunks (256 rows x 4 chunks of 16B),
    // 2 chunks/thread. LDS dest linear; SOURCE pre-swizzled:
    // logical chunk = physical ^ ((row>>1)&3)  (r4/r6/r10 proven-zero layout).
    size_t ga[2], gb[2];
    int lb[2];
    #pragma unroll
    for (int j = 0; j < 2; ++j) {
        int ch = wid * 128 + j * 64 + lane;
        int row = ch >> 2, qp = ch & 3;
        int qs = qp ^ ((row >> 1) & 3);
        ga[j] = (size_t)(bm + row) * K_DIM + qs * 8;
        gb[j] = (size_t)(bn + row) * K_DIM + qs * 8;
        lb[j] = (wid * 128 + j * 64) * 8;    // wave-uniform, HW adds lane*16B
    }

    // fragment reads: row r, chunk lk -> physical lk ^ ((r>>1)&3)
    const int lr = lane & 15, lk = lane >> 4;
    int aoff[8], boff[4], colj[4];
    #pragma unroll
    for (int i = 0; i < 8; ++i) {
        int ra = wr * 128 + i * 16 + lr;
        aoff[i] = ra * 32 + (lk ^ ((ra >> 1) & 3)) * 8;
    }
    #pragma unroll
    for (int j = 0; j < 4; ++j) {
        int rb = wc * 64 + j * 16 + lr;
        boff[j] = rb * 32 + (lk ^ ((rb >> 1) & 3)) * 8;
        colj[j] = bn + wc * 64 + j * 16 + lr;
    }

    f32x4 acc[8][4];
    #pragma unroll
    for (int i = 0; i < 8; ++i)
        #pragma unroll
        for (int j = 0; j < 4; ++j) acc[i][j] = {0.f, 0.f, 0.f, 0.f};

#define STAGE(tt)                                                                                      \
    {                                                                                                  \
        const int _sl = ((tt) & 3) * 16384;                                                            \
        _Pragma("unroll")                                                                              \
        for (int j = 0; j < 2; ++j) {                                                                  \
            __builtin_amdgcn_global_load_lds(AS1(A + ga[j] + (tt) * 32), AS3(&sm[_sl + lb[j]]), 16, 0, 0); \
            __builtin_amdgcn_global_load_lds(AS1(B + gb[j] + (tt) * 32), AS3(&sm[_sl + 8192 + lb[j]]), 16, 0, 0); \
        }                                                                                              \
    }

#define COMPUTE(tt)                                                                                    \
    {                                                                                                  \
        const unsigned short* _pa = &sm[((tt) & 3) * 16384];                                           \
        const unsigned short* _pb = _pa + 8192;                                                        \
        s8v av[8], bv[4];                                                                              \
        _Pragma("unroll")                                                                              \
        for (int i = 0; i < 8; ++i) av[i] = *reinterpret_cast<const s8v*>(&_pa[aoff[i]]);              \
        _Pragma("unroll")                                                                              \
        for (int j = 0; j < 4; ++j) bv[j] = *reinterpret_cast<const s8v*>(&_pb[boff[j]]);              \
        _Pragma("unroll")                                                                              \
        for (int i = 0; i < 8; ++i)                                                                    \
            _Pragma("unroll")                                                                          \
            for (int j = 0; j < 4; ++j)                                                                \
                acc[i][j] = __builtin_amdgcn_mfma_f32_16x16x32_bf16(av[i], bv[j], acc[i][j], 0, 0, 0); \
    }

#define SYNCN(N)                                                                                       \
    asm volatile("s_waitcnt vmcnt(" #N ")" ::: "memory");                                              \
    __builtin_amdgcn_s_barrier();                                                                      \
    __builtin_amdgcn_sched_barrier(0);

    // prologue: stage tiles 0,1,2 (12 loads/thread); retire tile 0
    // (vmcnt(8) leaves tiles 1,2 = 8 loads in flight)
    STAGE(0);
    STAGE(1);
    STAGE(2);
    SYNCN(8);
    // steady state: entering iter t, tiles t+1,t+2 issued (8 outstanding);
    // issue t+3 (slot (t-1)&3, freed by iter t-1's readers+barrier),
    // compute t, retire t+1's 4 oldest keeping t+2,t+3's 8 in flight.
    for (int t = 0; t + 3 < NT; ++t) {
        STAGE(t + 3);
        COMPUTE(t);
        SYNCN(8);
    }
    // tail: tiles NT-2, NT-1 in flight (8 loads)
    COMPUTE(NT - 3);
    SYNCN(4);          // retire tile NT-2's loads
    COMPUTE(NT - 2);
    SYNCN(0);          // retire tile NT-1's loads
    COMPUTE(NT - 1);
#undef STAGE
#undef COMPUTE
#undef SYNCN

    // epilogue — C/D frag layout: col = lane&15, row = (lane>>4)*4 + reg  [m89]
    if (MODE == 0) {
        #pragma unroll
        for (int i = 0; i < 8; ++i)
            #pragma unroll
            for (int j = 0; j < 4; ++j)
                #pragma unroll
                for (int r = 0; r < 4; ++r) {
                    int row = bm + wr * 128 + i * 16 + lk * 4 + r;
                    Cb[(size_t)row * K_DIM + colj[j]] = bf16_rne(acc[i][j][r]);
                }
    } else {
        float bj[4];
        #pragma unroll
        for (int j = 0; j < 4; ++j) bj[j] = bias[colj[j]];
        #pragma unroll
        for (int i = 0; i < 8; ++i)
            #pragma unroll
            for (int j = 0; j < 4; ++j)
                #pragma unroll
                for (int r = 0; r < 4; ++r) {
                    int row = bm + wr * 128 + i * 16 + lk * 4 + r;
                    Cf[(size_t)row * M_DIM + colj[j]] = acc[i][j][r] + bj[j];
                }
    }
}

extern "C" void kernel_launch(void* const* d_in, const int* in_sizes, int n_in,
                              void* d_out, int out_size, void* d_ws, size_t ws_size,
                              hipStream_t stream) {
    const float* x      = (const float*)d_in[0];
    const float* had    = (const float*)d_in[1];
    const float* wscale = (const float*)d_in[2];
    const float* bias   = (const float*)d_in[3];
    const int*   wdata  = (const int*)d_in[4];
    float* out = (float*)d_out;

    const size_t SEG = (size_t)N_TOK * K_DIM * 2;   // 32 MiB
    char* w = (char*)d_ws;
    unsigned short* xh  = (unsigned short*)(w);            // [0,32Mi)
    unsigned short* Hh  = (unsigned short*)(w + SEG);      // [32,64Mi)
    unsigned short* xrh = (unsigned short*)(w + 2 * SEG);  // [64,96Mi)
    unsigned short* Wb  = (unsigned short*)(w + 3 * SEG);  // [96,128Mi)

    // allow 128 KiB dynamic LDS (host-side idempotent config; guarded so the
    // graph-captured replay path never re-executes it — proven r10/r11)
    static bool attr_done = false;
    if (!attr_done) {
        hipFuncSetAttribute((const void*)gemm_cv<0>,
                            hipFuncAttributeMaxDynamicSharedMemorySize, 131072);
        hipFuncSetAttribute((const void*)gemm_cv<1>,
                            hipFuncAttributeMaxDynamicSharedMemorySize, 131072);
        attr_done = true;
    }

    prep_cast<<<(N_TOK * K_DIM) / (256 * 8), 256, 0, stream>>>(x, xh);
    prep_hT<<<dim3(64, 64), 256, 0, stream>>>(had, Hh);
    prep_w<<<M_DIM, 256, 0, stream>>>(wdata, wscale, Wb);
    gemm_cv<0><<<256, 512, 131072, stream>>>(xh, Hh, nullptr, xrh, nullptr);
    gemm_cv<1><<<256, 512, 131072, stream>>>(xrh, Wb, bias, nullptr, out);
}